// Round 8
// baseline (239.380 us; speedup 1.0000x reference)
//
#include <hip/hip_runtime.h>
#include <math.h>

// EuclideanCodebook: N=131072 rows x d=128 fp32, K=1024 codes.
// bf16x3 split-precision MFMA (xh*eh + xl*eh + xh*el), per-row top-2 gap
// tracking, exact fp32 recheck of rows with gap < TAU.
// Session ledger (measured, main-kernel dur):
//   R0  141 us  32-rows/wave, 2-dbuf LDS staging, plain __syncthreads  <- BEST
//   R6  174 us  no-LDS direct-global B (no prefetch distance)          REVERT
//   R7  156 us  counted vmcnt + raw barriers + setprio                 REVERT
//   R8  177 us  64 rows/wave -> VGPR spill (WRITE +48GB)               REVERT
//   R9  226 us  bf16x2 + TAU=0.25 -> 3% flagged x 512KB L2 rescan      REVERT
//   R10 235 us  tile-pair staging -> 70KB LDS -> occupancy 21->13%     REVERT
//   R11 156 us  acc init = -||e||^2 VGPR broadcast put an L1 load on
//               the MFMA chain head of EVERY tile (post-barrier, nothing
//               hides it). Prescale + early-stage existed only for that
//               init. ALL REVERTED.
// R12 (this round): R0 byte-level structure + exactly two proven deltas:
//   (a) v_med3_f32 2nd-best: epilogue 6->5 ops/score, cs still consumed
//       LATE (acc init 0, fmaf(2,sum,ncsq) -- load latency hidden as in R0);
//   (b) fused recheck tail (R9b/R11-proven): 2 launches, no global list.

typedef __attribute__((ext_vector_type(8)))  short short8_t;   // 8 bf16
typedef __attribute__((ext_vector_type(16))) float floatx16;   // 32x32 C frag

constexpr int D        = 128;
constexpr int KCODES   = 1024;
constexpr int NTILES   = 32;      // 1024 / 32 codes-per-tile
constexpr int ROWS_BLK = 128;     // 4 waves x 32 rows
constexpr float TAU    = 0.015f;  // >> 5-sigma bf16x3 score error (~2e-3)

// ws layout (bytes); total ~1.05 MB
constexpr size_t WS_NCSQ = 0;                      // 1024 f32, NEGATED ||e||^2
constexpr size_t WS_EHI  = 4096;                   // 1024*128 ushort, swizzled
constexpr size_t WS_ELO  = WS_EHI + 262144;
constexpr size_t WS_EMBT = WS_ELO + 262144;        // 128*1024 f32 transposed

#define GLOBAL_AS __attribute__((address_space(1)))
#define LDS_AS    __attribute__((address_space(3)))

__device__ inline unsigned short bf16_rne(float v, float* back) {
    unsigned u = __float_as_uint(v);
    unsigned r = (u + 0x7FFFu + ((u >> 16) & 1u)) >> 16;
    *back = __uint_as_float(r << 16);
    return (unsigned short)r;
}

// ------- prep: ncsq + swizzled bf16 hi/lo codebook + transposed codebook -------
// R0-verbatim (16 blocks x 64 threads); csq stored NEGATED, counter gone.
__global__ void ecb_prep(const float* __restrict__ embed, float* __restrict__ ncsq,
                         unsigned short* __restrict__ ehi, unsigned short* __restrict__ elo,
                         float* __restrict__ embT) {
    int n = blockIdx.x * 64 + threadIdx.x;
    if (n >= KCODES) return;
    const int t = n >> 5, nn = n & 31, nm = nn & 15;
    const float* row = embed + (size_t)n * D;
    const size_t tb = (size_t)t * 32 * D + (size_t)nn * D;
    float s = 0.f;
#pragma unroll
    for (int cc = 0; cc < 16; ++cc) {
        float4 a  = *(const float4*)(row + cc * 8);
        float4 bq = *(const float4*)(row + cc * 8 + 4);
        s = fmaf(a.x, a.x, s);  s = fmaf(a.y, a.y, s);
        s = fmaf(a.z, a.z, s);  s = fmaf(a.w, a.w, s);
        s = fmaf(bq.x, bq.x, s); s = fmaf(bq.y, bq.y, s);
        s = fmaf(bq.z, bq.z, s); s = fmaf(bq.w, bq.w, s);
        float vv[8] = {a.x, a.y, a.z, a.w, bq.x, bq.y, bq.z, bq.w};
#pragma unroll
        for (int j = 0; j < 8; ++j) embT[(size_t)(cc * 8 + j) * KCODES + n] = vv[j];
        unsigned short h[8], l[8];
#pragma unroll
        for (int j = 0; j < 8; ++j) {
            float hb, db;
            h[j] = bf16_rne(vv[j], &hb);
            l[j] = bf16_rne(vv[j] - hb, &db);
        }
        uint4 ph, pl;
        ph.x = (unsigned)h[0] | ((unsigned)h[1] << 16);
        ph.y = (unsigned)h[2] | ((unsigned)h[3] << 16);
        ph.z = (unsigned)h[4] | ((unsigned)h[5] << 16);
        ph.w = (unsigned)h[6] | ((unsigned)h[7] << 16);
        pl.x = (unsigned)l[0] | ((unsigned)l[1] << 16);
        pl.y = (unsigned)l[2] | ((unsigned)l[3] << 16);
        pl.z = (unsigned)l[4] | ((unsigned)l[5] << 16);
        pl.w = (unsigned)l[6] | ((unsigned)l[7] << 16);
        // XOR swizzle on the 16B chunk index -> conflict-free ds_read_b128 later
        size_t dst = tb + (size_t)((cc ^ nm) * 8);
        *(uint4*)(ehi + dst) = ph;
        *(uint4*)(elo + dst) = pl;
    }
    ncsq[n] = -s;
}

// ---------------- main: MFMA scores + argmax + fused exact recheck ----------------
__global__ __launch_bounds__(256, 3)
void ecb_main(const float* __restrict__ x,
              const unsigned short* __restrict__ ehi, const unsigned short* __restrict__ elo,
              const float* __restrict__ ncsq, const float* __restrict__ embed,
              const float* __restrict__ embT,
              float* __restrict__ out_idx, float* __restrict__ out_q) {
    __shared__ unsigned short ebuf[2][2][4096];   // [dbuf][hi/lo][32 codes x 128], 32 KB
    __shared__ int sidx[ROWS_BLK];                // 512 B
    __shared__ unsigned char llist[ROWS_BLK];
    __shared__ unsigned lcount;

    const int tid  = threadIdx.x;
    const int lane = tid & 63, wave = tid >> 6;
    const int col  = lane & 31, h = lane >> 5, colm = col & 15;
    const long rowblk = (long)blockIdx.x * ROWS_BLK;
    const int  roww   = wave * 32;

    if (tid == 0) lcount = 0u;

    // A prologue: 32 rows/wave of x -> bf16 hi/lo fragments in registers (R0 order).
    short8_t ah[8], al[8];
    {
        const float* xr = x + (rowblk + roww + col) * (long)D + h * 8;
#pragma unroll
        for (int c = 0; c < 8; ++c) {
            float4 a  = *(const float4*)(xr + c * 16);
            float4 bq = *(const float4*)(xr + c * 16 + 4);
            float vv[8] = {a.x, a.y, a.z, a.w, bq.x, bq.y, bq.z, bq.w};
            short8_t fh, fl;
#pragma unroll
            for (int j = 0; j < 8; ++j) {
                float hb, db;
                fh[j] = (short)bf16_rne(vv[j], &hb);
                fl[j] = (short)bf16_rne(vv[j] - hb, &db);
            }
            ah[c] = fh;
            al[c] = fl;
        }
    }

    auto stage = [&](int t, int b) {
        const char* gh = (const char*)(ehi) + (size_t)t * 8192;
        const char* gl = (const char*)(elo) + (size_t)t * 8192;
        char* lh = (char*)&ebuf[b][0][0];
        char* ll = (char*)&ebuf[b][1][0];
#pragma unroll
        for (int i = 0; i < 2; ++i) {
            int off = i * 4096 + wave * 1024;
            __builtin_amdgcn_global_load_lds((const GLOBAL_AS unsigned int*)(gh + off + lane * 16),
                                             (LDS_AS unsigned int*)(lh + off), 16, 0, 0);
            __builtin_amdgcn_global_load_lds((const GLOBAL_AS unsigned int*)(gl + off + lane * 16),
                                             (LDS_AS unsigned int*)(ll + off), 16, 0, 0);
        }
    };

    float v1[16], v2[16];
#pragma unroll
    for (int j = 0; j < 16; ++j) { v1[j] = -INFINITY; v2[j] = -INFINITY; }

    stage(0, 0);
    __syncthreads();

#pragma unroll 1
    for (int t = 0; t < NTILES; ++t) {
        const int b = t & 1;
        if (t + 1 < NTILES) stage(t + 1, (t + 1) & 1);

        const float negcs = ncsq[t * 32 + col];   // L1-hot; first USE is epilogue

        floatx16 accA, accB;   // 2 independent chains, init 0 (no load on chain head)
#pragma unroll
        for (int i = 0; i < 16; ++i) { accA[i] = 0.f; accB[i] = 0.f; }

        // FULL unroll: constant indices keep ah[s]/al[s] in registers (R3 bug).
#pragma unroll
        for (int s = 0; s < 8; ++s) {
            const int cc = 2 * s + h;
            const int idx = (col * 16 + (cc ^ colm)) * 8;   // elements
            short8_t bh = *(const short8_t*)&ebuf[b][0][idx];
            short8_t bl = *(const short8_t*)&ebuf[b][1][idx];
            accA = __builtin_amdgcn_mfma_f32_32x32x16_bf16(ah[s], bh, accA, 0, 0, 0);
            accB = __builtin_amdgcn_mfma_f32_32x32x16_bf16(al[s], bh, accB, 0, 0, 0);
            accB = __builtin_amdgcn_mfma_f32_32x32x16_bf16(ah[s], bl, accB, 0, 0, 0);
        }

        // epilogue: score = 2*(accA+accB) - ||e||^2 ; 5 VALU/score (med3 2nd-best)
#pragma unroll
        for (int j = 0; j < 16; ++j) {
            float sc = fmaf(2.f, accA[j] + accB[j], negcs);
            unsigned u = (__float_as_uint(sc) & ~31u) | (unsigned)t;
            float cand = __uint_as_float(u);
            float vo = v1[j];
            v1[j] = fmaxf(vo, cand);
            v2[j] = __builtin_amdgcn_fmed3f(vo, v2[j], cand);  // 2nd-best
        }
        __syncthreads();
    }

    // cross-lane top-2 merge over the 32 columns of each half
#pragma unroll
    for (int j = 0; j < 16; ++j) {
        float a1 = v1[j], a2 = v2[j];
        int   c1 = (int)((__float_as_uint(a1) & 31u) << 5) | col;   // tile*32 + col
#pragma unroll
        for (int m = 1; m < 32; m <<= 1) {
            float o1 = __shfl_xor(a1, m, 64);
            int   oc = __shfl_xor(c1, m, 64);
            float o2 = __shfl_xor(a2, m, 64);
            float lo = fminf(a1, o1);
            if (o1 > a1) { a1 = o1; c1 = oc; }
            a2 = fmaxf(fmaxf(a2, o2), lo);
        }
        if (col == j) {
            int row_local = roww + (j & 3) + 8 * (j >> 2) + 4 * h;
            sidx[row_local] = c1;
            out_idx[rowblk + row_local] = (float)c1;
            if (a1 - a2 < TAU) {                      // ties always land here
                unsigned p = atomicAdd(&lcount, 1u);  // <= 128 by construction
                llist[p] = (unsigned char)row_local;
            }
        }
    }
    __syncthreads();

    // gather quantize = embed[best] (exact fp32 values, L2-hot)
    for (int i = tid; i < ROWS_BLK * 32; i += 256) {
        int r = i >> 5, q = i & 31;
        int code = sidx[r];
        float4 ev = *(const float4*)(embed + (size_t)code * D + q * 4);
        *(float4*)(out_q + (rowblk + r) * (long)D + q * 4) = ev;
    }
    __syncthreads();

    // fused exact fp32 recheck of this block's flagged rows (~0.2/block at
    // TAU=0.015). R9b-proven code; coalesced embT reads; scratch aliases ebuf.
    float* xs = (float*)&ebuf[0][0][0];           // 128 f32
    float* bv = xs + D;                           // 256 f32
    int*   bi = (int*)(bv + 256);                 // 256 i32
    const unsigned nf = lcount;
    const float4* eT = (const float4*)embT;       // [k][256 x float4-of-codes]
    for (unsigned f = 0; f < nf; ++f) {
        const int rl  = llist[f];
        const long row = rowblk + rl;
        if (tid < 32) *(float4*)&xs[tid * 4] = *(const float4*)(x + row * D + tid * 4);
        __syncthreads();
        float4 dot = {0.f, 0.f, 0.f, 0.f};
#pragma unroll 8
        for (int k = 0; k < D; ++k) {
            float xv = xs[k];
            float4 e = eT[(size_t)k * 256 + tid];
            dot.x = fmaf(xv, e.x, dot.x);
            dot.y = fmaf(xv, e.y, dot.y);
            dot.z = fmaf(xv, e.z, dot.z);
            dot.w = fmaf(xv, e.w, dot.w);
        }
        const int c0 = tid * 4;
        float4 nc = *(const float4*)(ncsq + c0);
        float scs[4] = {fmaf(2.f, dot.x, nc.x),
                        fmaf(2.f, dot.y, nc.y),
                        fmaf(2.f, dot.z, nc.z),
                        fmaf(2.f, dot.w, nc.w)};
        float best = -INFINITY; int bidx = 0;
#pragma unroll
        for (int i = 0; i < 4; ++i)
            if (scs[i] > best) { best = scs[i]; bidx = c0 + i; }
        bv[tid] = best; bi[tid] = bidx;
        __syncthreads();
        for (int s = 128; s > 0; s >>= 1) {
            if (tid < s) {
                float ov = bv[tid + s]; int oi = bi[tid + s];
                if (ov > bv[tid] || (ov == bv[tid] && oi < bi[tid])) { bv[tid] = ov; bi[tid] = oi; }
            }
            __syncthreads();
        }
        const int win = bi[0];
        if (tid == 0) out_idx[row] = (float)win;
        if (tid < 32) {
            float4 ev = *(const float4*)(embed + (size_t)win * D + tid * 4);
            *(float4*)(out_q + row * D + tid * 4) = ev;
        }
        __syncthreads();
    }
}

extern "C" void kernel_launch(void* const* d_in, const int* in_sizes, int n_in,
                              void* d_out, int out_size, void* d_ws, size_t ws_size,
                              hipStream_t stream) {
    const float* x     = (const float*)d_in[0];
    const float* embed = (const float*)d_in[1];
    const int N = in_sizes[0] / D;   // 131072
    char* ws = (char*)d_ws;
    float*          ncsq = (float*)(ws + WS_NCSQ);
    unsigned short* ehi  = (unsigned short*)(ws + WS_EHI);
    unsigned short* elo  = (unsigned short*)(ws + WS_ELO);
    float*          embT = (float*)(ws + WS_EMBT);
    float* out_idx = (float*)d_out;
    float* out_q   = out_idx + N;

    hipLaunchKernelGGL(ecb_prep, dim3(16), dim3(64), 0, stream,
                       embed, ncsq, ehi, elo, embT);
    hipLaunchKernelGGL(ecb_main, dim3(N / ROWS_BLK), dim3(256), 0, stream,
                       x, ehi, elo, ncsq, embed, embT, out_idx, out_q);
}